// Round 6
// baseline (211.877 us; speedup 1.0000x reference)
//
#include <hip/hip_runtime.h>
#include <hip/hip_bf16.h>

// SCNN round 6:
//  - conv GEMM: fused hi/lo accumulator (M=256 real rows), BM=64 BN=128 BK=32,
//    uniform split-K chunks of 1024 (sk 2/4/2) -> 768 identical blocks (3/CU),
//    bank swizzle slot ^= (row>>1)&3 on both staging source and LDS reads
//  - k_cvtL grid-strided (12 float4/thread)
//  - epi0: slot-sum + relu*P/M + hi/lo re-split; epi1s: slot-sum + relu*P/M +
//    sum over S directly into hsum (k_sums eliminated)
//  - MLP: round-5 BW-shaped split-K (unchanged)

#define B_    32
#define S_    8
#define BS_   256
#define F_    4
#define IN_   8192
#define H_    1024
#define OUT_  256

#define L_TOT  25165824LL     // 2048^2 + 4096^2 + 2048^2
#define LOFF1  4194304LL
#define LOFF2  20971520LL

typedef __attribute__((ext_vector_type(8)))  short bf16x8;
typedef __attribute__((ext_vector_type(4)))  short short4v;
typedef __attribute__((ext_vector_type(16))) float f32x16;

typedef const __attribute__((address_space(1))) void* gas_ptr;
typedef __attribute__((address_space(3))) void* las_ptr;

__device__ __forceinline__ void gload16(const void* g, void* s) {
    __builtin_amdgcn_global_load_lds((gas_ptr)g, (las_ptr)s, 16, 0, 0);
}

__device__ __forceinline__ unsigned short rne_bf16(float f) {
    unsigned int u = __builtin_bit_cast(unsigned int, f);
    u += 0x7FFFu + ((u >> 16) & 1u);
    return (unsigned short)(u >> 16);
}

// ---------------- P/M from Wc ----------------
__global__ void k_prep(const float* __restrict__ Wc0, const float* __restrict__ Wc1,
                       const float* __restrict__ Wc2, float* __restrict__ PM) {
    int idx = blockIdx.x * 256 + threadIdx.x;
    if (idx >= 2 * IN_) return;
    int l = idx / IN_, n = idx % IN_;
    const float* Wc; int nb, j;
    if (n < 2048)      { Wc = Wc0; nb = 2048; j = n;        }
    else if (n < 6144) { Wc = Wc1; nb = 4096; j = n - 2048; }
    else               { Wc = Wc2; nb = 2048; j = n - 6144; }
    float p = 0.f, m = 0.f;
    #pragma unroll
    for (int f = 0; f < F_; ++f) {
        float w = Wc[(l * F_ + f) * nb + j];
        p += fmaxf(w, 0.f);
        m += fmaxf(-w, 0.f);
    }
    PM[(l * 2 + 0) * IN_ + n] = p;
    PM[(l * 2 + 1) * IN_ + n] = m;
}

// ---------------- L f32 -> bf16 (concat), grid-strided ----------------
__global__ void k_cvtL(const float* __restrict__ L0, const float* __restrict__ L1,
                       const float* __restrict__ L2, unsigned short* __restrict__ Lb) {
    const int gid = blockIdx.x * 256 + threadIdx.x;   // 524288 threads
    #pragma unroll 4
    for (int it = 0; it < 12; ++it) {
        long long e = ((long long)it * 524288 + gid) * 4;
        const float* src; long long off;
        if (e < LOFF1)      { src = L0; off = 0; }
        else if (e < LOFF2) { src = L1; off = LOFF1; }
        else                { src = L2; off = LOFF2; }
        float4 v = *(const float4*)(src + (e - off));
        short4v o;
        o.x = (short)rne_bf16(v.x); o.y = (short)rne_bf16(v.y);
        o.z = (short)rne_bf16(v.z); o.w = (short)rne_bf16(v.w);
        *(short4v*)(Lb + e) = o;
    }
}

// ---------------- xs -> hi/lo bf16 [256][8192] each ----------------
__global__ void k_splitX(const float* __restrict__ x0, const float* __restrict__ x1,
                         const float* __restrict__ x2,
                         unsigned short* __restrict__ Xhi, unsigned short* __restrict__ Xlo) {
    int e = (blockIdx.x * 256 + threadIdx.x) * 4;
    int m = e >> 13, c = e & 8191;
    const float* src; int n, c0;
    if (c < 2048)      { src = x0; n = 2048; c0 = c; }
    else if (c < 6144) { src = x1; n = 4096; c0 = c - 2048; }
    else               { src = x2; n = 2048; c0 = c - 6144; }
    float4 v = *(const float4*)(src + (size_t)m * n + c0);
    float a[4] = {v.x, v.y, v.z, v.w};
    short hv[4], lv[4];
    #pragma unroll
    for (int i = 0; i < 4; ++i) {
        unsigned short hb = rne_bf16(a[i]);
        float hf = __builtin_bit_cast(float, (unsigned int)hb << 16);
        hv[i] = (short)hb;
        lv[i] = (short)rne_bf16(a[i] - hf);
    }
    short4v h = {hv[0], hv[1], hv[2], hv[3]};
    short4v l = {lv[0], lv[1], lv[2], lv[3]};
    *(short4v*)(Xhi + (size_t)m * IN_ + c) = h;
    *(short4v*)(Xlo + (size_t)m * IN_ + c) = l;
}

// ---------------- MFMA GEMM: pf[sl][256][8192] += Xhi.L^T + Xlo.L^T ----------------
// 768 blocks, all K-chunk = 1024 (32 iters of BK=32).
// b0: bx<128: sk2 x (4 mt x 16 nt); b1: 128..639: sk4 x (4 x 32); b2: 640..767.
// BM=64 BN=128, 4 waves (2x2), wave-tile 32x64, hi/lo fused into acc.
__global__ __launch_bounds__(256, 3) void k_gemm(
    const unsigned short* __restrict__ Xhi, const unsigned short* __restrict__ Xlo,
    const unsigned short* __restrict__ Lb,
    float* __restrict__ pf)                    // [4][256][8192]
{
    __shared__ __attribute__((aligned(16))) unsigned short Ah[2][64 * 32];
    __shared__ __attribute__((aligned(16))) unsigned short Al[2][64 * 32];
    __shared__ __attribute__((aligned(16))) unsigned short Bs[2][128 * 32];

    const int bx = blockIdx.x;
    int n_, noff, mt, nt, sk; long long loff;
    if (bx < 128) {
        int u = bx; sk = u & 1; u >>= 1; mt = u >> 4; nt = u & 15;
        n_ = 2048; noff = 0; loff = 0;
    } else if (bx < 640) {
        int u = bx - 128; sk = u & 3; u >>= 2; mt = u >> 5; nt = u & 31;
        n_ = 4096; noff = 2048; loff = LOFF1;
    } else {
        int u = bx - 640; sk = u & 1; u >>= 1; mt = u >> 4; nt = u & 15;
        n_ = 2048; noff = 6144; loff = LOFF2;
    }
    const int k0 = sk << 10;                    // uniform K-chunk of 1024

    const int tid = threadIdx.x, l = tid & 63, w = tid >> 6;

    // ----- staging source (pre-swizzled global cols: slot_g = (l&3)^((l>>3)&3)) -----
    const int sr  = 16 * w + (l >> 2);          // row in tile covered by this lane
    const int slg = (((l & 3) ^ ((l >> 3) & 3)) << 3);  // elem offset
    const unsigned short* gAh = Xhi + (size_t)(mt * 64 + sr) * IN_ + noff + k0 + slg;
    const unsigned short* gAl = Xlo + (size_t)(mt * 64 + sr) * IN_ + noff + k0 + slg;
    const unsigned short* gB0 = Lb + loff + (size_t)(nt * 128 + sr) * n_ + k0 + slg;
    const unsigned short* gB1 = Lb + loff + (size_t)(nt * 128 + 64 + sr) * n_ + k0 + slg;
    char* dAh[2] = {(char*)&Ah[0][0] + w * 1024, (char*)&Ah[1][0] + w * 1024};
    char* dAl[2] = {(char*)&Al[0][0] + w * 1024, (char*)&Al[1][0] + w * 1024};
    char* dB0[2] = {(char*)&Bs[0][0] + w * 1024, (char*)&Bs[1][0] + w * 1024};
    char* dB1[2] = {(char*)&Bs[0][0] + 4096 + w * 1024, (char*)&Bs[1][0] + 4096 + w * 1024};

    // ----- compute-side addressing -----
    const int l31 = l & 31, lh = l >> 5;
    const int wm = w >> 1, wn = w & 1;
    const int ra  = (wm * 32 + l31) * 32;       // ushort idx row base (A)
    const int rb0 = (wn * 64 + l31) * 32;       // B j-block 0
    const int rb1 = rb0 + 32 * 32;              // B j-block 1
    const int swz = ((l31 >> 1) & 3);

    f32x16 acc0, acc1;
    #pragma unroll
    for (int r = 0; r < 16; ++r) { acc0[r] = 0.f; acc1[r] = 0.f; }

    // prologue
    gload16(gAh, dAh[0]); gload16(gAl, dAl[0]);
    gload16(gB0, dB0[0]); gload16(gB1, dB1[0]);
    __syncthreads();

    for (int it = 0; it < 32; ++it) {
        const int cur = it & 1, nxt = cur ^ 1;
        if (it + 1 < 32) {
            const int ko = (it + 1) * 32;
            gload16(gAh + ko, dAh[nxt]); gload16(gAl + ko, dAl[nxt]);
            gload16(gB0 + ko, dB0[nxt]); gload16(gB1 + ko, dB1[nxt]);
        }
        #pragma unroll
        for (int t = 0; t < 2; ++t) {
            const int sidx = (((2 * t + lh) ^ swz) << 3);
            bf16x8 fah = *(const bf16x8*)&Ah[cur][ra + sidx];
            bf16x8 fal = *(const bf16x8*)&Al[cur][ra + sidx];
            bf16x8 fb0 = *(const bf16x8*)&Bs[cur][rb0 + sidx];
            bf16x8 fb1 = *(const bf16x8*)&Bs[cur][rb1 + sidx];
            acc0 = __builtin_amdgcn_mfma_f32_32x32x16_bf16(fal, fb0, acc0, 0, 0, 0);
            acc0 = __builtin_amdgcn_mfma_f32_32x32x16_bf16(fah, fb0, acc0, 0, 0, 0);
            acc1 = __builtin_amdgcn_mfma_f32_32x32x16_bf16(fal, fb1, acc1, 0, 0, 0);
            acc1 = __builtin_amdgcn_mfma_f32_32x32x16_bf16(fah, fb1, acc1, 0, 0, 0);
        }
        __syncthreads();
    }

    // ----- partial store: pf[sk][m][col] -----
    const int colg = noff + nt * 128 + wn * 64 + l31;
    float* po = pf + ((size_t)sk * 256 + (size_t)mt * 64 + wm * 32 + 4 * lh) * IN_;
    #pragma unroll
    for (int r = 0; r < 16; ++r) {
        int row = (r & 3) + 8 * (r >> 2);
        po[(size_t)row * IN_ + colg]      = acc0[r];
        po[(size_t)row * IN_ + colg + 32] = acc1[r];
    }
}

// ---------------- epi0: slot-sum + relu*P/M + hi/lo re-split ----------------
__global__ void k_epi0(const float* __restrict__ pf,
                       const float* __restrict__ Pv, const float* __restrict__ Mv,
                       unsigned short* __restrict__ Yhi, unsigned short* __restrict__ Ylo) {
    int e = (blockIdx.x * 256 + threadIdx.x) * 4;   // over [256][8192]
    int m = e >> 13, c = e & 8191;
    const int nsl = (c >= 2048 && c < 6144) ? 4 : 2;
    const float* p0 = pf + (size_t)m * IN_ + c;
    float vs[4] = {0.f, 0.f, 0.f, 0.f};
    for (int s = 0; s < nsl; ++s) {
        float4 v = *(const float4*)(p0 + (size_t)s * 256 * IN_);
        vs[0] += v.x; vs[1] += v.y; vs[2] += v.z; vs[3] += v.w;
    }
    float4 pv = *(const float4*)(Pv + c);
    float4 mv = *(const float4*)(Mv + c);
    float pa[4] = {pv.x, pv.y, pv.z, pv.w};
    float ma[4] = {mv.x, mv.y, mv.z, mv.w};
    short hv[4], lv[4];
    #pragma unroll
    for (int j = 0; j < 4; ++j) {
        float y = fmaxf(vs[j], 0.f) * pa[j] + fmaxf(-vs[j], 0.f) * ma[j];
        unsigned short hb = rne_bf16(y);
        float hf = __builtin_bit_cast(float, (unsigned int)hb << 16);
        hv[j] = (short)hb;
        lv[j] = (short)rne_bf16(y - hf);
    }
    short4v h = {hv[0], hv[1], hv[2], hv[3]};
    short4v lo = {lv[0], lv[1], lv[2], lv[3]};
    *(short4v*)(Yhi + (size_t)m * IN_ + c) = h;
    *(short4v*)(Ylo + (size_t)m * IN_ + c) = lo;
}

// ---------------- epi1s: slot-sum + relu*P/M + sum over S -> hsum ----------------
__global__ void k_epi1s(const float* __restrict__ pf,
                        const float* __restrict__ Pv, const float* __restrict__ Mv,
                        float* __restrict__ hsum) {
    int e = (blockIdx.x * 256 + threadIdx.x) * 4;   // over [32][8192]
    int b = e >> 13, c = e & 8191;
    const int nsl = (c >= 2048 && c < 6144) ? 4 : 2;
    float4 pv = *(const float4*)(Pv + c);
    float4 mv = *(const float4*)(Mv + c);
    float pa[4] = {pv.x, pv.y, pv.z, pv.w};
    float ma[4] = {mv.x, mv.y, mv.z, mv.w};
    float hs[4] = {0.f, 0.f, 0.f, 0.f};
    for (int q = 0; q < 8; ++q) {
        const int m = b * 8 + q;
        const float* p0 = pf + (size_t)m * IN_ + c;
        float vs[4] = {0.f, 0.f, 0.f, 0.f};
        for (int s = 0; s < nsl; ++s) {
            float4 v = *(const float4*)(p0 + (size_t)s * 256 * IN_);
            vs[0] += v.x; vs[1] += v.y; vs[2] += v.z; vs[3] += v.w;
        }
        #pragma unroll
        for (int j = 0; j < 4; ++j)
            hs[j] += fmaxf(vs[j], 0.f) * pa[j] + fmaxf(-vs[j], 0.f) * ma[j];
    }
    *(float4*)(hsum + (size_t)b * IN_ + c) = *(float4*)hs;
}

// ---------------- MLP split-K partial GEMM (BW-shaped) ----------------
template<int KC>
__global__ __launch_bounds__(256) void k_mlp3(
    const float* __restrict__ X, const float* __restrict__ W,
    float* __restrict__ P, int K, int H)
{
    __shared__ float Xs[32][KC];
    const int tid = threadIdx.x;
    const int lane = tid & 63;
    const int mg = tid >> 6;
    const int h = (blockIdx.x * 64 + lane) * 4;
    const int c = blockIdx.y, k0 = c * KC;

    for (int i = tid * 4; i < 32 * KC; i += 1024) {
        int m = i / KC, kk = i % KC;
        *(float4*)&Xs[m][kk] = *(const float4*)(X + (size_t)m * K + k0 + kk);
    }
    __syncthreads();

    float4 acc[8];
    #pragma unroll
    for (int m = 0; m < 8; ++m) acc[m] = {0.f, 0.f, 0.f, 0.f};

    const float* wp = W + (size_t)k0 * H + h;
    for (int kk = 0; kk < KC; kk += 4) {
        float4 w4[4];
        #pragma unroll
        for (int u = 0; u < 4; ++u)
            w4[u] = *(const float4*)(wp + (size_t)(kk + u) * H);
        #pragma unroll
        for (int m = 0; m < 8; ++m) {
            float4 xv = *(const float4*)&Xs[mg * 8 + m][kk];
            acc[m].x = fmaf(xv.x, w4[0].x, acc[m].x);
            acc[m].y = fmaf(xv.x, w4[0].y, acc[m].y);
            acc[m].z = fmaf(xv.x, w4[0].z, acc[m].z);
            acc[m].w = fmaf(xv.x, w4[0].w, acc[m].w);
            acc[m].x = fmaf(xv.y, w4[1].x, acc[m].x);
            acc[m].y = fmaf(xv.y, w4[1].y, acc[m].y);
            acc[m].z = fmaf(xv.y, w4[1].z, acc[m].z);
            acc[m].w = fmaf(xv.y, w4[1].w, acc[m].w);
            acc[m].x = fmaf(xv.z, w4[2].x, acc[m].x);
            acc[m].y = fmaf(xv.z, w4[2].y, acc[m].y);
            acc[m].z = fmaf(xv.z, w4[2].z, acc[m].z);
            acc[m].w = fmaf(xv.z, w4[2].w, acc[m].w);
            acc[m].x = fmaf(xv.w, w4[3].x, acc[m].x);
            acc[m].y = fmaf(xv.w, w4[3].y, acc[m].y);
            acc[m].z = fmaf(xv.w, w4[3].z, acc[m].z);
            acc[m].w = fmaf(xv.w, w4[3].w, acc[m].w);
        }
    }
    #pragma unroll
    for (int m = 0; m < 8; ++m)
        *(float4*)(P + ((size_t)c * 32 + mg * 8 + m) * H + h) = acc[m];
}

// ---------------- reduce partials + bias (+relu), float4 ----------------
__global__ void k_reduce4(const float* __restrict__ P, const float* __restrict__ bias,
                          float* __restrict__ Y, int NC, int MH4, int H, int do_relu) {
    int idx = blockIdx.x * 256 + threadIdx.x;
    if (idx >= MH4) return;
    int h0 = (idx * 4) % H;
    float4 s = *(const float4*)(bias + h0);
    for (int c = 0; c < NC; ++c) {
        float4 v = *(const float4*)(P + (size_t)c * MH4 * 4 + (size_t)idx * 4);
        s.x += v.x; s.y += v.y; s.z += v.z; s.w += v.w;
    }
    if (do_relu) {
        s.x = fmaxf(s.x, 0.f); s.y = fmaxf(s.y, 0.f);
        s.z = fmaxf(s.z, 0.f); s.w = fmaxf(s.w, 0.f);
    }
    *(float4*)(Y + (size_t)idx * 4) = s;
}

extern "C" void kernel_launch(void* const* d_in, const int* in_sizes, int n_in,
                              void* d_out, int out_size, void* d_ws, size_t ws_size,
                              hipStream_t stream) {
    const float* xs0  = (const float*)d_in[0];
    const float* xs1  = (const float*)d_in[1];
    const float* xs2  = (const float*)d_in[2];
    const float* L0   = (const float*)d_in[3];
    const float* L1   = (const float*)d_in[4];
    const float* L2   = (const float*)d_in[5];
    const float* Wc0  = (const float*)d_in[6];
    const float* Wc1  = (const float*)d_in[7];
    const float* Wc2  = (const float*)d_in[8];
    const float* W_in = (const float*)d_in[9];
    const float* b_in = (const float*)d_in[10];
    const float* W_h  = (const float*)d_in[11];
    const float* b_h  = (const float*)d_in[12];
    const float* W_out= (const float*)d_in[13];
    const float* b_out= (const float*)d_in[14];

    char* w = (char*)d_ws;
    float*          PM  = (float*)w;          w += (size_t)4 * IN_ * 4;          // 128 KB
    unsigned short* Lb  = (unsigned short*)w; w += (size_t)L_TOT * 2;            // 50.3 MB
    unsigned short* Xhi = (unsigned short*)w; w += (size_t)BS_ * IN_ * 2;        // 4 MB
    unsigned short* Xlo = (unsigned short*)w; w += (size_t)BS_ * IN_ * 2;        // 4 MB
    unsigned short* Yhi = (unsigned short*)w; w += (size_t)BS_ * IN_ * 2;        // 4 MB
    unsigned short* Ylo = (unsigned short*)w; w += (size_t)BS_ * IN_ * 2;        // 4 MB
    float*          pf  = (float*)w;          w += (size_t)4 * BS_ * IN_ * 4;    // 32 MB
    float*          hsum= (float*)w;          w += (size_t)32 * IN_ * 4;         // 1 MB
    float*          p1  = pf;                 // alias: pf free after k_epi1s (16 MB used)
    float*          h1  = (float*)w;          w += (size_t)32 * H_ * 4;
    float*          p2  = (float*)w;          w += (size_t)32 * 32 * H_ * 4;     // 4 MB
    float*          h2  = (float*)w;          w += (size_t)32 * H_ * 4;
    float*          p3  = (float*)w;          w += (size_t)32 * 32 * OUT_ * 4;   // 1 MB

    k_prep<<<64, 256, 0, stream>>>(Wc0, Wc1, Wc2, PM);
    k_cvtL<<<2048, 256, 0, stream>>>(L0, L1, L2, Lb);
    k_splitX<<<2048, 256, 0, stream>>>(xs0, xs1, xs2, Xhi, Xlo);

    k_gemm<<<768, 256, 0, stream>>>(Xhi, Xlo, Lb, pf);
    k_epi0<<<2048, 256, 0, stream>>>(pf, PM + 0 * IN_, PM + 1 * IN_, Yhi, Ylo);
    k_gemm<<<768, 256, 0, stream>>>(Yhi, Ylo, Lb, pf);
    k_epi1s<<<256, 256, 0, stream>>>(pf, PM + 2 * IN_, PM + 3 * IN_, hsum);

    {   // [32,8192]@[8192,1024]: grid (4 h-tiles, 128 k-chunks of 64)
        dim3 g(4, 128);
        k_mlp3<64><<<g, 256, 0, stream>>>(hsum, W_in, p1, IN_, H_);
        k_reduce4<<<32, 256, 0, stream>>>(p1, b_in, h1, 128, 8192, H_, 1);
    }
    {   // [32,1024]@[1024,1024]: grid (4, 32 chunks of 32)
        dim3 g(4, 32);
        k_mlp3<32><<<g, 256, 0, stream>>>(h1, W_h, p2, H_, H_);
        k_reduce4<<<32, 256, 0, stream>>>(p2, b_h, h2, 32, 8192, H_, 1);
    }
    {   // [32,1024]@[1024,256]: grid (1, 32 chunks of 32)
        dim3 g(1, 32);
        k_mlp3<32><<<g, 256, 0, stream>>>(h2, W_out, p3, H_, OUT_);
        k_reduce4<<<8, 256, 0, stream>>>(p3, b_out, (float*)d_out, 32, 2048, OUT_, 0);
    }
}

// Round 7
// 199.248 us; speedup vs baseline: 1.0634x; 1.0634x over previous
//
#include <hip/hip_runtime.h>
#include <hip/hip_bf16.h>

// SCNN round 7:
//  - k_gemm: ring-3 LDS (48KB), counted s_waitcnt vmcnt(4) + raw s_barrier
//    (T4: next stage's loads stay in flight across the barrier), 1 barrier/iter
//  - k_pre: fused L->bf16 convert + x hi/lo split + P/M build (one launch)
//  - epi0 / epi1s / BW-shaped MLP unchanged from round 6

#define B_    32
#define S_    8
#define BS_   256
#define F_    4
#define IN_   8192
#define H_    1024
#define OUT_  256

#define L_TOT  25165824LL     // 2048^2 + 4096^2 + 2048^2
#define LOFF1  4194304LL
#define LOFF2  20971520LL

typedef __attribute__((ext_vector_type(8)))  short bf16x8;
typedef __attribute__((ext_vector_type(4)))  short short4v;
typedef __attribute__((ext_vector_type(8)))  short short8v;
typedef __attribute__((ext_vector_type(16))) float f32x16;

typedef const __attribute__((address_space(1))) void* gas_ptr;
typedef __attribute__((address_space(3))) void* las_ptr;

__device__ __forceinline__ void gload16(const void* g, void* s) {
    __builtin_amdgcn_global_load_lds((gas_ptr)g, (las_ptr)s, 16, 0, 0);
}

__device__ __forceinline__ unsigned short rne_bf16(float f) {
    unsigned int u = __builtin_bit_cast(unsigned int, f);
    u += 0x7FFFu + ((u >> 16) & 1u);
    return (unsigned short)(u >> 16);
}

// ---------------- fused prep: L->bf16, x->hi/lo, P/M ----------------
// grid 3592: [0,3072) cvtL (32 floats/thr), [3072,3584) splitX (16 floats/thr),
//            [3584,3592) prep P/M
__global__ void k_pre(const float* __restrict__ L0, const float* __restrict__ L1,
                      const float* __restrict__ L2, unsigned short* __restrict__ Lb,
                      const float* __restrict__ x0, const float* __restrict__ x1,
                      const float* __restrict__ x2,
                      unsigned short* __restrict__ Xhi, unsigned short* __restrict__ Xlo,
                      const float* __restrict__ Wc0, const float* __restrict__ Wc1,
                      const float* __restrict__ Wc2, float* __restrict__ PM)
{
    const int bx = blockIdx.x, tid = threadIdx.x;
    if (bx < 3072) {
        const long long base = (long long)bx * 8192 + tid * 8;
        #pragma unroll
        for (int u = 0; u < 4; ++u) {
            long long e = base + (long long)u * 2048;
            const float* src; long long off;
            if (e < LOFF1)      { src = L0; off = 0; }
            else if (e < LOFF2) { src = L1; off = LOFF1; }
            else                { src = L2; off = LOFF2; }
            const float* p = src + (e - off);
            float4 a = *(const float4*)(p);
            float4 b = *(const float4*)(p + 4);
            short8v o;
            o[0] = (short)rne_bf16(a.x); o[1] = (short)rne_bf16(a.y);
            o[2] = (short)rne_bf16(a.z); o[3] = (short)rne_bf16(a.w);
            o[4] = (short)rne_bf16(b.x); o[5] = (short)rne_bf16(b.y);
            o[6] = (short)rne_bf16(b.z); o[7] = (short)rne_bf16(b.w);
            *(short8v*)(Lb + e) = o;
        }
    } else if (bx < 3584) {
        const int base = (bx - 3072) * 4096 + tid * 8;
        #pragma unroll
        for (int u = 0; u < 2; ++u) {
            int e = base + u * 2048;
            int m = e >> 13, c = e & 8191;
            const float* src; int n, c0;
            if (c < 2048)      { src = x0; n = 2048; c0 = c; }
            else if (c < 6144) { src = x1; n = 4096; c0 = c - 2048; }
            else               { src = x2; n = 2048; c0 = c - 6144; }
            const float* p = src + (size_t)m * n + c0;
            float4 a = *(const float4*)(p);
            float4 b = *(const float4*)(p + 4);
            float v[8] = {a.x, a.y, a.z, a.w, b.x, b.y, b.z, b.w};
            short8v h, l;
            #pragma unroll
            for (int i = 0; i < 8; ++i) {
                unsigned short hb = rne_bf16(v[i]);
                float hf = __builtin_bit_cast(float, (unsigned int)hb << 16);
                h[i] = (short)hb;
                l[i] = (short)rne_bf16(v[i] - hf);
            }
            *(short8v*)(Xhi + (size_t)m * IN_ + c) = h;
            *(short8v*)(Xlo + (size_t)m * IN_ + c) = l;
        }
    } else {
        const int base = (bx - 3584) * 2048 + tid * 8;
        #pragma unroll
        for (int i = 0; i < 8; ++i) {
            int idx = base + i;
            int l = idx / IN_, n = idx % IN_;
            const float* Wc; int nb, j;
            if (n < 2048)      { Wc = Wc0; nb = 2048; j = n;        }
            else if (n < 6144) { Wc = Wc1; nb = 4096; j = n - 2048; }
            else               { Wc = Wc2; nb = 2048; j = n - 6144; }
            float p = 0.f, m = 0.f;
            #pragma unroll
            for (int f = 0; f < F_; ++f) {
                float w = Wc[(l * F_ + f) * nb + j];
                p += fmaxf(w, 0.f);
                m += fmaxf(-w, 0.f);
            }
            PM[(l * 2 + 0) * IN_ + n] = p;
            PM[(l * 2 + 1) * IN_ + n] = m;
        }
    }
}

// ---------------- MFMA GEMM: ring-3 LDS, counted vmcnt ----------------
// 768 blocks, uniform K-chunk 1024 (32 iters of BK=32).
// b0: bx<128 (sk2 x 4mt x 16nt); b1: 128..639 (sk4 x 4 x 32); b2: 640..767.
// BM=64 BN=128, 4 waves (2x2), wave-tile 32x64, hi/lo fused into acc.
__global__ __launch_bounds__(256, 3) void k_gemm(
    const unsigned short* __restrict__ Xhi, const unsigned short* __restrict__ Xlo,
    const unsigned short* __restrict__ Lb,
    float* __restrict__ pf)                    // [4][256][8192]
{
    __shared__ __attribute__((aligned(16))) unsigned short Ah[3][64 * 32];
    __shared__ __attribute__((aligned(16))) unsigned short Al[3][64 * 32];
    __shared__ __attribute__((aligned(16))) unsigned short Bs[3][128 * 32];

    const int bx = blockIdx.x;
    int n_, noff, mt, nt, sk; long long loff;
    if (bx < 128) {
        int u = bx; sk = u & 1; u >>= 1; mt = u >> 4; nt = u & 15;
        n_ = 2048; noff = 0; loff = 0;
    } else if (bx < 640) {
        int u = bx - 128; sk = u & 3; u >>= 2; mt = u >> 5; nt = u & 31;
        n_ = 4096; noff = 2048; loff = LOFF1;
    } else {
        int u = bx - 640; sk = u & 1; u >>= 1; mt = u >> 4; nt = u & 15;
        n_ = 2048; noff = 6144; loff = LOFF2;
    }
    const int k0 = sk << 10;                    // uniform K-chunk of 1024

    const int tid = threadIdx.x, l = tid & 63, w = tid >> 6;

    // staging source (pre-swizzled global cols: slot_g = (l&3)^((l>>3)&3))
    const int sr  = 16 * w + (l >> 2);
    const int slg = (((l & 3) ^ ((l >> 3) & 3)) << 3);
    const unsigned short* gAh = Xhi + (size_t)(mt * 64 + sr) * IN_ + noff + k0 + slg;
    const unsigned short* gAl = Xlo + (size_t)(mt * 64 + sr) * IN_ + noff + k0 + slg;
    const unsigned short* gB0 = Lb + loff + (size_t)(nt * 128 + sr) * n_ + k0 + slg;
    const unsigned short* gB1 = Lb + loff + (size_t)(nt * 128 + 64 + sr) * n_ + k0 + slg;

    // compute-side addressing
    const int l31 = l & 31, lh = l >> 5;
    const int wm = w >> 1, wn = w & 1;
    const int ra  = (wm * 32 + l31) * 32;
    const int rb0 = (wn * 64 + l31) * 32;
    const int rb1 = rb0 + 32 * 32;
    const int swz = ((l31 >> 1) & 3);

    f32x16 acc0, acc1;
    #pragma unroll
    for (int r = 0; r < 16; ++r) { acc0[r] = 0.f; acc1[r] = 0.f; }

    #define STAGE(slot, ko)                                                     \
        do {                                                                    \
            gload16(gAh + (ko), (char*)&Ah[slot][0] + w * 1024);                \
            gload16(gAl + (ko), (char*)&Al[slot][0] + w * 1024);                \
            gload16(gB0 + (ko), (char*)&Bs[slot][0] + w * 1024);                \
            gload16(gB1 + (ko), (char*)&Bs[slot][0] + 4096 + w * 1024);         \
        } while (0)

    // prologue: 2 stages in flight
    STAGE(0, 0);
    STAGE(1, 32);

    for (int it = 0; it < 32; ++it) {
        // wait for stage(it) only; keep stage(it+1)'s 4 loads in flight
        if (it + 1 < 32) asm volatile("s_waitcnt vmcnt(4)" ::: "memory");
        else             asm volatile("s_waitcnt vmcnt(0)" ::: "memory");
        __builtin_amdgcn_s_barrier();
        asm volatile("" ::: "memory");

        if (it + 2 < 32) {
            const int slot = (it + 2) % 3;
            const int ko = (it + 2) * 32;
            STAGE(slot, ko);
        }
        __builtin_amdgcn_sched_barrier(0);

        const int cur = it % 3;
        #pragma unroll
        for (int t = 0; t < 2; ++t) {
            const int sidx = (((2 * t + lh) ^ swz) << 3);
            bf16x8 fah = *(const bf16x8*)&Ah[cur][ra + sidx];
            bf16x8 fal = *(const bf16x8*)&Al[cur][ra + sidx];
            bf16x8 fb0 = *(const bf16x8*)&Bs[cur][rb0 + sidx];
            bf16x8 fb1 = *(const bf16x8*)&Bs[cur][rb1 + sidx];
            acc0 = __builtin_amdgcn_mfma_f32_32x32x16_bf16(fal, fb0, acc0, 0, 0, 0);
            acc0 = __builtin_amdgcn_mfma_f32_32x32x16_bf16(fah, fb0, acc0, 0, 0, 0);
            acc1 = __builtin_amdgcn_mfma_f32_32x32x16_bf16(fal, fb1, acc1, 0, 0, 0);
            acc1 = __builtin_amdgcn_mfma_f32_32x32x16_bf16(fah, fb1, acc1, 0, 0, 0);
        }
        asm volatile("" ::: "memory");
    }
    #undef STAGE

    // partial store: pf[sk][m][col]
    const int colg = noff + nt * 128 + wn * 64 + l31;
    float* po = pf + ((size_t)sk * 256 + (size_t)mt * 64 + wm * 32 + 4 * lh) * IN_;
    #pragma unroll
    for (int r = 0; r < 16; ++r) {
        int row = (r & 3) + 8 * (r >> 2);
        po[(size_t)row * IN_ + colg]      = acc0[r];
        po[(size_t)row * IN_ + colg + 32] = acc1[r];
    }
}

// ---------------- epi0: slot-sum + relu*P/M + hi/lo re-split ----------------
__global__ void k_epi0(const float* __restrict__ pf,
                       const float* __restrict__ Pv, const float* __restrict__ Mv,
                       unsigned short* __restrict__ Yhi, unsigned short* __restrict__ Ylo) {
    int e = (blockIdx.x * 256 + threadIdx.x) * 4;   // over [256][8192]
    int m = e >> 13, c = e & 8191;
    const int nsl = (c >= 2048 && c < 6144) ? 4 : 2;
    const float* p0 = pf + (size_t)m * IN_ + c;
    float vs[4] = {0.f, 0.f, 0.f, 0.f};
    for (int s = 0; s < nsl; ++s) {
        float4 v = *(const float4*)(p0 + (size_t)s * 256 * IN_);
        vs[0] += v.x; vs[1] += v.y; vs[2] += v.z; vs[3] += v.w;
    }
    float4 pv = *(const float4*)(Pv + c);
    float4 mv = *(const float4*)(Mv + c);
    float pa[4] = {pv.x, pv.y, pv.z, pv.w};
    float ma[4] = {mv.x, mv.y, mv.z, mv.w};
    short hv[4], lv[4];
    #pragma unroll
    for (int j = 0; j < 4; ++j) {
        float y = fmaxf(vs[j], 0.f) * pa[j] + fmaxf(-vs[j], 0.f) * ma[j];
        unsigned short hb = rne_bf16(y);
        float hf = __builtin_bit_cast(float, (unsigned int)hb << 16);
        hv[j] = (short)hb;
        lv[j] = (short)rne_bf16(y - hf);
    }
    short4v h = {hv[0], hv[1], hv[2], hv[3]};
    short4v lo = {lv[0], lv[1], lv[2], lv[3]};
    *(short4v*)(Yhi + (size_t)m * IN_ + c) = h;
    *(short4v*)(Ylo + (size_t)m * IN_ + c) = lo;
}

// ---------------- epi1s: slot-sum + relu*P/M + sum over S -> hsum ----------------
__global__ void k_epi1s(const float* __restrict__ pf,
                        const float* __restrict__ Pv, const float* __restrict__ Mv,
                        float* __restrict__ hsum) {
    int e = (blockIdx.x * 256 + threadIdx.x) * 4;   // over [32][8192]
    int b = e >> 13, c = e & 8191;
    const int nsl = (c >= 2048 && c < 6144) ? 4 : 2;
    float4 pv = *(const float4*)(Pv + c);
    float4 mv = *(const float4*)(Mv + c);
    float pa[4] = {pv.x, pv.y, pv.z, pv.w};
    float ma[4] = {mv.x, mv.y, mv.z, mv.w};
    float hs[4] = {0.f, 0.f, 0.f, 0.f};
    for (int q = 0; q < 8; ++q) {
        const int m = b * 8 + q;
        const float* p0 = pf + (size_t)m * IN_ + c;
        float vs[4] = {0.f, 0.f, 0.f, 0.f};
        for (int s = 0; s < nsl; ++s) {
            float4 v = *(const float4*)(p0 + (size_t)s * 256 * IN_);
            vs[0] += v.x; vs[1] += v.y; vs[2] += v.z; vs[3] += v.w;
        }
        #pragma unroll
        for (int j = 0; j < 4; ++j)
            hs[j] += fmaxf(vs[j], 0.f) * pa[j] + fmaxf(-vs[j], 0.f) * ma[j];
    }
    *(float4*)(hsum + (size_t)b * IN_ + c) = *(float4*)hs;
}

// ---------------- MLP split-K partial GEMM (BW-shaped) ----------------
template<int KC>
__global__ __launch_bounds__(256) void k_mlp3(
    const float* __restrict__ X, const float* __restrict__ W,
    float* __restrict__ P, int K, int H)
{
    __shared__ float Xs[32][KC];
    const int tid = threadIdx.x;
    const int lane = tid & 63;
    const int mg = tid >> 6;
    const int h = (blockIdx.x * 64 + lane) * 4;
    const int c = blockIdx.y, k0 = c * KC;

    for (int i = tid * 4; i < 32 * KC; i += 1024) {
        int m = i / KC, kk = i % KC;
        *(float4*)&Xs[m][kk] = *(const float4*)(X + (size_t)m * K + k0 + kk);
    }
    __syncthreads();

    float4 acc[8];
    #pragma unroll
    for (int m = 0; m < 8; ++m) acc[m] = {0.f, 0.f, 0.f, 0.f};

    const float* wp = W + (size_t)k0 * H + h;
    for (int kk = 0; kk < KC; kk += 4) {
        float4 w4[4];
        #pragma unroll
        for (int u = 0; u < 4; ++u)
            w4[u] = *(const float4*)(wp + (size_t)(kk + u) * H);
        #pragma unroll
        for (int m = 0; m < 8; ++m) {
            float4 xv = *(const float4*)&Xs[mg * 8 + m][kk];
            acc[m].x = fmaf(xv.x, w4[0].x, acc[m].x);
            acc[m].y = fmaf(xv.x, w4[0].y, acc[m].y);
            acc[m].z = fmaf(xv.x, w4[0].z, acc[m].z);
            acc[m].w = fmaf(xv.x, w4[0].w, acc[m].w);
            acc[m].x = fmaf(xv.y, w4[1].x, acc[m].x);
            acc[m].y = fmaf(xv.y, w4[1].y, acc[m].y);
            acc[m].z = fmaf(xv.y, w4[1].z, acc[m].z);
            acc[m].w = fmaf(xv.y, w4[1].w, acc[m].w);
            acc[m].x = fmaf(xv.z, w4[2].x, acc[m].x);
            acc[m].y = fmaf(xv.z, w4[2].y, acc[m].y);
            acc[m].z = fmaf(xv.z, w4[2].z, acc[m].z);
            acc[m].w = fmaf(xv.z, w4[2].w, acc[m].w);
            acc[m].x = fmaf(xv.w, w4[3].x, acc[m].x);
            acc[m].y = fmaf(xv.w, w4[3].y, acc[m].y);
            acc[m].z = fmaf(xv.w, w4[3].z, acc[m].z);
            acc[m].w = fmaf(xv.w, w4[3].w, acc[m].w);
        }
    }
    #pragma unroll
    for (int m = 0; m < 8; ++m)
        *(float4*)(P + ((size_t)c * 32 + mg * 8 + m) * H + h) = acc[m];
}

// ---------------- reduce partials + bias (+relu), float4 ----------------
__global__ void k_reduce4(const float* __restrict__ P, const float* __restrict__ bias,
                          float* __restrict__ Y, int NC, int MH4, int H, int do_relu) {
    int idx = blockIdx.x * 256 + threadIdx.x;
    if (idx >= MH4) return;
    int h0 = (idx * 4) % H;
    float4 s = *(const float4*)(bias + h0);
    for (int c = 0; c < NC; ++c) {
        float4 v = *(const float4*)(P + (size_t)c * MH4 * 4 + (size_t)idx * 4);
        s.x += v.x; s.y += v.y; s.z += v.z; s.w += v.w;
    }
    if (do_relu) {
        s.x = fmaxf(s.x, 0.f); s.y = fmaxf(s.y, 0.f);
        s.z = fmaxf(s.z, 0.f); s.w = fmaxf(s.w, 0.f);
    }
    *(float4*)(Y + (size_t)idx * 4) = s;
}

extern "C" void kernel_launch(void* const* d_in, const int* in_sizes, int n_in,
                              void* d_out, int out_size, void* d_ws, size_t ws_size,
                              hipStream_t stream) {
    const float* xs0  = (const float*)d_in[0];
    const float* xs1  = (const float*)d_in[1];
    const float* xs2  = (const float*)d_in[2];
    const float* L0   = (const float*)d_in[3];
    const float* L1   = (const float*)d_in[4];
    const float* L2   = (const float*)d_in[5];
    const float* Wc0  = (const float*)d_in[6];
    const float* Wc1  = (const float*)d_in[7];
    const float* Wc2  = (const float*)d_in[8];
    const float* W_in = (const float*)d_in[9];
    const float* b_in = (const float*)d_in[10];
    const float* W_h  = (const float*)d_in[11];
    const float* b_h  = (const float*)d_in[12];
    const float* W_out= (const float*)d_in[13];
    const float* b_out= (const float*)d_in[14];

    char* w = (char*)d_ws;
    float*          PM  = (float*)w;          w += (size_t)4 * IN_ * 4;          // 128 KB
    unsigned short* Lb  = (unsigned short*)w; w += (size_t)L_TOT * 2;            // 50.3 MB
    unsigned short* Xhi = (unsigned short*)w; w += (size_t)BS_ * IN_ * 2;        // 4 MB
    unsigned short* Xlo = (unsigned short*)w; w += (size_t)BS_ * IN_ * 2;        // 4 MB
    unsigned short* Yhi = (unsigned short*)w; w += (size_t)BS_ * IN_ * 2;        // 4 MB
    unsigned short* Ylo = (unsigned short*)w; w += (size_t)BS_ * IN_ * 2;        // 4 MB
    float*          pf  = (float*)w;          w += (size_t)4 * BS_ * IN_ * 4;    // 32 MB
    float*          hsum= (float*)w;          w += (size_t)32 * IN_ * 4;         // 1 MB
    float*          p1  = pf;                 // alias: pf free after k_epi1s
    float*          h1  = (float*)w;          w += (size_t)32 * H_ * 4;
    float*          p2  = (float*)w;          w += (size_t)32 * 32 * H_ * 4;     // 4 MB
    float*          h2  = (float*)w;          w += (size_t)32 * H_ * 4;
    float*          p3  = (float*)w;          w += (size_t)32 * 32 * OUT_ * 4;   // 1 MB

    k_pre<<<3592, 256, 0, stream>>>(L0, L1, L2, Lb, xs0, xs1, xs2, Xhi, Xlo,
                                    Wc0, Wc1, Wc2, PM);

    k_gemm<<<768, 256, 0, stream>>>(Xhi, Xlo, Lb, pf);
    k_epi0<<<2048, 256, 0, stream>>>(pf, PM + 0 * IN_, PM + 1 * IN_, Yhi, Ylo);
    k_gemm<<<768, 256, 0, stream>>>(Yhi, Ylo, Lb, pf);
    k_epi1s<<<256, 256, 0, stream>>>(pf, PM + 2 * IN_, PM + 3 * IN_, hsum);

    {   // [32,8192]@[8192,1024]: grid (4 h-tiles, 128 k-chunks of 64)
        dim3 g(4, 128);
        k_mlp3<64><<<g, 256, 0, stream>>>(hsum, W_in, p1, IN_, H_);
        k_reduce4<<<32, 256, 0, stream>>>(p1, b_in, h1, 128, 8192, H_, 1);
    }
    {   // [32,1024]@[1024,1024]: grid (4, 32 chunks of 32)
        dim3 g(4, 32);
        k_mlp3<32><<<g, 256, 0, stream>>>(h1, W_h, p2, H_, H_);
        k_reduce4<<<32, 256, 0, stream>>>(p2, b_h, h2, 32, 8192, H_, 1);
    }
    {   // [32,1024]@[1024,256]: grid (1, 32 chunks of 32)
        dim3 g(1, 32);
        k_mlp3<32><<<g, 256, 0, stream>>>(h2, W_out, p3, H_, OUT_);
        k_reduce4<<<8, 256, 0, stream>>>(p3, b_out, (float*)d_out, 32, 2048, OUT_, 0);
    }
}